// Round 8
// baseline (415.386 us; speedup 1.0000x reference)
//
#include <hip/hip_runtime.h>

#define N_NODES 100000
#define N_EDGES 3200000
#define NB 1024                        // buckets: 4 agg blocks per CU
#define BKN 98                         // nodes per bucket (1024*98=100352)
#define RSZ 3968                       // record window (mean 3136, +14.9 sigma)
#define TILE 6250
#define NTILES 512                     // 512*6250 == 3.2M exactly; 2 blocks/CU
#define MAXIT 13                       // ceil(TILE/512)
#define ACCS 100                       // sacc row stride (bank de-correlation)

// ---------------------------------------------------------------------------
// r7 lessons: fixed-slot 144B segments re-created partial-line RMW (130MB
// writes) AND 3-dispatch didn't help -> dispatch overhead is small; the two
// gather kernels (~110us combined) are the real cost. This round: keep the
// proven r2 proj/scatter/agg2 bodies, replace the layer-1 LDS counting sort
// (atomic-rank/scan/place/re-read + 2 barriers + dependent-address gathers)
// with DIRECT LDS f32 accumulation: stream recs coalesced, 16 ds_add_f32
// per record into sacc[16][100] (stride 100 spreads banks by node), gather
// addresses come straight from the linear load (deep MLP, no LDS dep chain).
// ---------------------------------------------------------------------------

__device__ __forceinline__ float bf2f_lo(unsigned int w) {
  return __uint_as_float(w << 16);
}
__device__ __forceinline__ float bf2f_hi(unsigned int w) {
  return __uint_as_float(w & 0xFFFF0000u);
}
__device__ __forceinline__ unsigned short f2bf(float f) {
  unsigned int b = __float_as_uint(f);
  return (unsigned short)((b + 0x7FFFu + ((b >> 16) & 1u)) >> 16);
}

// proj1 + gcur zero-init. 256-thread blocks x 391 (round-2 proven).
__global__ __launch_bounds__(256) void k_proj1(
    const float* __restrict__ x, const float* __restrict__ Wl1,
    const float* __restrict__ Wr1, const float* __restrict__ b1,
    unsigned short* __restrict__ p1h, float* __restrict__ q1b,
    int* __restrict__ gcur) {
  __shared__ float sWl[512];
  __shared__ float sWr[512];
  __shared__ float sb[16];
  const int t = threadIdx.x;
  if (t < 64) {
    const int gi = blockIdx.x * 64 + t;
    if (gi < NB * 16) gcur[gi] = 0;
  }
  for (int i = t; i < 512; i += 256) {
    sWl[i] = Wl1[i];
    sWr[i] = Wr1[i];
  }
  if (t < 16) sb[t] = b1[t];
  __syncthreads();

  const int n = blockIdx.x * 256 + t;
  if (n >= N_NODES) return;

  float xr[32];
  const float4* xp = (const float4*)(x + (size_t)n * 32);
#pragma unroll
  for (int j = 0; j < 8; ++j) {
    float4 v = xp[j];
    xr[4 * j + 0] = v.x;
    xr[4 * j + 1] = v.y;
    xr[4 * j + 2] = v.z;
    xr[4 * j + 3] = v.w;
  }
  float pv[16], qv[16];
#pragma unroll
  for (int hh = 0; hh < 16; ++hh) {
    float a = 0.f, b = 0.f;
#pragma unroll
    for (int i = 0; i < 32; ++i) {
      a = fmaf(xr[i], sWl[hh * 32 + i], a);
      b = fmaf(xr[i], sWr[hh * 32 + i], b);
    }
    pv[hh] = a;
    qv[hh] = b + sb[hh];
  }
  unsigned int w[8];
#pragma unroll
  for (int j = 0; j < 8; ++j)
    w[j] = (unsigned int)f2bf(pv[2 * j]) |
           ((unsigned int)f2bf(pv[2 * j + 1]) << 16);
  uint4* pp = (uint4*)(p1h + (size_t)n * 16);
  pp[0] = make_uint4(w[0], w[1], w[2], w[3]);
  pp[1] = make_uint4(w[4], w[5], w[6], w[7]);
  float4* qp = (float4*)(q1b + (size_t)n * 16);
#pragma unroll
  for (int j = 0; j < 4; ++j)
    qp[j] = make_float4(qv[4 * j], qv[4 * j + 1], qv[4 * j + 2], qv[4 * j + 3]);
}

// Tile counting-sort scatter (round-2 proven body). 512x512 = 2/CU.
__global__ __launch_bounds__(512) void k_bscatter(const int* __restrict__ ei,
                                                  int* __restrict__ gcur,
                                                  int* __restrict__ recs) {
  __shared__ int hist[1024];
  __shared__ int delta[NB];
  __shared__ int seg[512];
  __shared__ int stage[TILE];
  __shared__ unsigned short bid[TILE + 6];
  const int t = threadIdx.x;
  for (int i = t; i < 1024; i += 512) hist[i] = 0;
  __syncthreads();

  const int tb = blockIdx.x * TILE;
  int rec[MAXIT], aux[MAXIT];  // aux = (bucket<<16) | rank
#pragma unroll
  for (int i = 0; i < MAXIT; ++i) {
    const int pos = t + i * 512;
    if (pos < TILE) {
      const int e = tb + pos;
      const int s = ei[e];
      const int d = ei[N_EDGES + e];
      const int k = (int)((unsigned)d / (unsigned)BKN);
      const int rank = atomicAdd(&hist[k], 1);
      rec[i] = ((d - k * BKN) << 17) | s;
      aux[i] = (k << 16) | rank;
    } else {
      aux[i] = -1;
    }
  }
  __syncthreads();

  const int s0 = hist[2 * t], s1 = hist[2 * t + 1];
  const int my = s0 + s1;
  seg[t] = my;
  __syncthreads();
#pragma unroll
  for (int o = 1; o < 512; o <<= 1) {
    const int a = (t >= o) ? seg[t - o] : 0;
    __syncthreads();
    seg[t] += a;
    __syncthreads();
  }
  const int ex = seg[t] - my;
  hist[2 * t] = ex;
  hist[2 * t + 1] = ex + s0;
  {
    const int b = 2 * t;
    if (s0) delta[b] = b * RSZ + atomicAdd(&gcur[b * 16], s0) - ex;
    if (s1)
      delta[b + 1] =
          (b + 1) * RSZ + atomicAdd(&gcur[(b + 1) * 16], s1) - (ex + s0);
  }
  __syncthreads();

#pragma unroll
  for (int i = 0; i < MAXIT; ++i) {
    if (aux[i] >= 0) stage[hist[aux[i] >> 16] + (aux[i] & 0xFFFF)] = rec[i];
  }
  for (int k2 = t; k2 < NB; k2 += 512) {
    const int st = hist[k2];
    const int en = (k2 == NB - 1) ? TILE : hist[k2 + 1];
    for (int p = st; p < en; ++p) bid[p] = (unsigned short)k2;
  }
  __syncthreads();

  for (int pos = t; pos < TILE; pos += 512) {
    const int bb = bid[pos];
    const int idx = delta[bb] + pos;
    if (idx < (bb + 1) * RSZ) recs[idx] = stage[pos];
  }
}

// Layer-1 DIRECT aggregation (sort-free): stream recs coalesced, 16
// ds_add_f32 per record into sacc[16][ACCS], then finish + layer-2 proj.
// 1024 blocks x 512 = 4 blocks/CU (LDS 7KB).
__global__ __launch_bounds__(512, 8) void k_agg1(
    const int* __restrict__ gcur, const int* __restrict__ recs,
    const unsigned short* __restrict__ p1h, const float* __restrict__ q1b,
    const float* __restrict__ Wl2, const float* __restrict__ Wr2,
    float* __restrict__ p2, float* __restrict__ r2,
    float* __restrict__ deg_inv) {
  __shared__ float sacc[16 * ACCS];  // [ch][local], stride 100
  __shared__ int hist[128];
  __shared__ float sWl[16], sWr[16];
  const int t = threadIdx.x;
  const int kb = blockIdx.x;
  for (int i = t; i < 16 * ACCS; i += 512) sacc[i] = 0.f;
  if (t < 128) hist[t] = 0;
  if (t < 16) {
    sWl[t] = Wl2[t];
    sWr[t] = Wr2[t];
  }
  __syncthreads();

  const int b0 = kb * RSZ;
  const int cend = min(gcur[kb * 16], RSZ);

  // 2 records per iteration: 4 independent 16B gathers in flight
  int r = t;
  for (; r + 512 < cend; r += 1024) {
    const int rv0 = recs[b0 + r];
    const int rv1 = recs[b0 + r + 512];
    const int l0 = rv0 >> 17, l1 = rv1 >> 17;
    const uint4* pa = (const uint4*)(p1h + (size_t)(rv0 & 0x1FFFF) * 16);
    const uint4* pc = (const uint4*)(p1h + (size_t)(rv1 & 0x1FFFF) * 16);
    const uint4 a0 = pa[0], a1 = pa[1];
    const uint4 c0 = pc[0], c1 = pc[1];
    atomicAdd(&hist[l0], 1);
    atomicAdd(&hist[l1], 1);
    float* s0 = sacc + l0;
    float* s1 = sacc + l1;
    atomicAdd(s0 + 0 * ACCS, bf2f_lo(a0.x));
    atomicAdd(s0 + 1 * ACCS, bf2f_hi(a0.x));
    atomicAdd(s0 + 2 * ACCS, bf2f_lo(a0.y));
    atomicAdd(s0 + 3 * ACCS, bf2f_hi(a0.y));
    atomicAdd(s0 + 4 * ACCS, bf2f_lo(a0.z));
    atomicAdd(s0 + 5 * ACCS, bf2f_hi(a0.z));
    atomicAdd(s0 + 6 * ACCS, bf2f_lo(a0.w));
    atomicAdd(s0 + 7 * ACCS, bf2f_hi(a0.w));
    atomicAdd(s0 + 8 * ACCS, bf2f_lo(a1.x));
    atomicAdd(s0 + 9 * ACCS, bf2f_hi(a1.x));
    atomicAdd(s0 + 10 * ACCS, bf2f_lo(a1.y));
    atomicAdd(s0 + 11 * ACCS, bf2f_hi(a1.y));
    atomicAdd(s0 + 12 * ACCS, bf2f_lo(a1.z));
    atomicAdd(s0 + 13 * ACCS, bf2f_hi(a1.z));
    atomicAdd(s0 + 14 * ACCS, bf2f_lo(a1.w));
    atomicAdd(s0 + 15 * ACCS, bf2f_hi(a1.w));
    atomicAdd(s1 + 0 * ACCS, bf2f_lo(c0.x));
    atomicAdd(s1 + 1 * ACCS, bf2f_hi(c0.x));
    atomicAdd(s1 + 2 * ACCS, bf2f_lo(c0.y));
    atomicAdd(s1 + 3 * ACCS, bf2f_hi(c0.y));
    atomicAdd(s1 + 4 * ACCS, bf2f_lo(c0.z));
    atomicAdd(s1 + 5 * ACCS, bf2f_hi(c0.z));
    atomicAdd(s1 + 6 * ACCS, bf2f_lo(c0.w));
    atomicAdd(s1 + 7 * ACCS, bf2f_hi(c0.w));
    atomicAdd(s1 + 8 * ACCS, bf2f_lo(c1.x));
    atomicAdd(s1 + 9 * ACCS, bf2f_hi(c1.x));
    atomicAdd(s1 + 10 * ACCS, bf2f_lo(c1.y));
    atomicAdd(s1 + 11 * ACCS, bf2f_hi(c1.y));
    atomicAdd(s1 + 12 * ACCS, bf2f_lo(c1.z));
    atomicAdd(s1 + 13 * ACCS, bf2f_hi(c1.z));
    atomicAdd(s1 + 14 * ACCS, bf2f_lo(c1.w));
    atomicAdd(s1 + 15 * ACCS, bf2f_hi(c1.w));
  }
  if (r < cend) {
    const int rv0 = recs[b0 + r];
    const int l0 = rv0 >> 17;
    const uint4* pa = (const uint4*)(p1h + (size_t)(rv0 & 0x1FFFF) * 16);
    const uint4 a0 = pa[0], a1 = pa[1];
    atomicAdd(&hist[l0], 1);
    float* s0 = sacc + l0;
    atomicAdd(s0 + 0 * ACCS, bf2f_lo(a0.x));
    atomicAdd(s0 + 1 * ACCS, bf2f_hi(a0.x));
    atomicAdd(s0 + 2 * ACCS, bf2f_lo(a0.y));
    atomicAdd(s0 + 3 * ACCS, bf2f_hi(a0.y));
    atomicAdd(s0 + 4 * ACCS, bf2f_lo(a0.z));
    atomicAdd(s0 + 5 * ACCS, bf2f_hi(a0.z));
    atomicAdd(s0 + 6 * ACCS, bf2f_lo(a0.w));
    atomicAdd(s0 + 7 * ACCS, bf2f_hi(a0.w));
    atomicAdd(s0 + 8 * ACCS, bf2f_lo(a1.x));
    atomicAdd(s0 + 9 * ACCS, bf2f_hi(a1.x));
    atomicAdd(s0 + 10 * ACCS, bf2f_lo(a1.y));
    atomicAdd(s0 + 11 * ACCS, bf2f_hi(a1.y));
    atomicAdd(s0 + 12 * ACCS, bf2f_lo(a1.z));
    atomicAdd(s0 + 13 * ACCS, bf2f_hi(a1.z));
    atomicAdd(s0 + 14 * ACCS, bf2f_lo(a1.w));
    atomicAdd(s0 + 15 * ACCS, bf2f_hi(a1.w));
  }
  __syncthreads();

  // finish: 2 lanes/node (half = channel half); layer-2 projection
  const int half = t & 1;
  const int local = t >> 1;  // 0..255 covers BKN=98
  if (local < BKN) {
    const int n = kb * BKN + local;
    if (n < N_NODES) {
      const int k = hist[local];
      const float di = 1.f / fmaxf((float)k, 1.f);
      const float4* qp = (const float4*)(q1b + (size_t)n * 16 + half * 8);
      const float4 qa = qp[0], qb = qp[1];
      const float* sa = sacc + local + half * 8 * ACCS;
      float h[8];
      h[0] = fmaxf(fmaf(sa[0 * ACCS], di, qa.x), 0.f);
      h[1] = fmaxf(fmaf(sa[1 * ACCS], di, qa.y), 0.f);
      h[2] = fmaxf(fmaf(sa[2 * ACCS], di, qa.z), 0.f);
      h[3] = fmaxf(fmaf(sa[3 * ACCS], di, qa.w), 0.f);
      h[4] = fmaxf(fmaf(sa[4 * ACCS], di, qb.x), 0.f);
      h[5] = fmaxf(fmaf(sa[5 * ACCS], di, qb.y), 0.f);
      h[6] = fmaxf(fmaf(sa[6 * ACCS], di, qb.z), 0.f);
      h[7] = fmaxf(fmaf(sa[7 * ACCS], di, qb.w), 0.f);
      float pa = 0.f, pbv = 0.f;
#pragma unroll
      for (int i = 0; i < 8; ++i) {
        pa = fmaf(h[i], sWl[half * 8 + i], pa);
        pbv = fmaf(h[i], sWr[half * 8 + i], pbv);
      }
      pa += __shfl_xor(pa, 1);
      pbv += __shfl_xor(pbv, 1);
      if (half == 0) {
        p2[n] = pa;
        r2[n] = pbv;
        deg_inv[n] = di;
      }
    }
  }
}

// layer-2 aggregation (round-2 proven body): linear recs + p2 gather +
// 1 LDS f32 atomicAdd per edge. 1024 blocks = 4/CU.
__global__ __launch_bounds__(512, 8) void k_agg2out(
    const int* __restrict__ gcur, const int* __restrict__ recs,
    const float* __restrict__ p2, const float* __restrict__ r2,
    const float* __restrict__ deg_inv, const float* __restrict__ b2,
    float* __restrict__ out) {
  __shared__ float acc[BKN];
  const int t = threadIdx.x;
  const int kb = blockIdx.x;
  if (t < BKN) acc[t] = 0.f;
  __syncthreads();

  const int b0 = kb * RSZ;
  const int cnt = min(gcur[kb * 16], RSZ);
  int r = t;
  for (; r + 1536 < cnt; r += 2048) {
    const int rv0 = recs[b0 + r];
    const int rv1 = recs[b0 + r + 512];
    const int rv2 = recs[b0 + r + 1024];
    const int rv3 = recs[b0 + r + 1536];
    const float v0 = p2[rv0 & 0x1FFFF];
    const float v1 = p2[rv1 & 0x1FFFF];
    const float v2 = p2[rv2 & 0x1FFFF];
    const float v3 = p2[rv3 & 0x1FFFF];
    atomicAdd(&acc[rv0 >> 17], v0);
    atomicAdd(&acc[rv1 >> 17], v1);
    atomicAdd(&acc[rv2 >> 17], v2);
    atomicAdd(&acc[rv3 >> 17], v3);
  }
  for (; r < cnt; r += 512) {
    const int rv = recs[b0 + r];
    atomicAdd(&acc[rv >> 17], p2[rv & 0x1FFFF]);
  }
  __syncthreads();

  if (t < BKN) {
    const int n = kb * BKN + t;
    if (n < N_NODES) out[n] = fmaf(acc[t], deg_inv[n], r2[n] + b2[0]);
  }
}

extern "C" void kernel_launch(void* const* d_in, const int* in_sizes, int n_in,
                              void* d_out, int out_size, void* d_ws,
                              size_t ws_size, hipStream_t stream) {
  const float* x   = (const float*)d_in[0];
  const int*   ei  = (const int*)d_in[1];
  const float* Wl1 = (const float*)d_in[2];
  const float* Wr1 = (const float*)d_in[3];
  const float* b1  = (const float*)d_in[4];
  const float* Wl2 = (const float*)d_in[5];
  const float* Wr2 = (const float*)d_in[6];
  const float* b2  = (const float*)d_in[7];
  float* out = (float*)d_out;

  const size_t N = N_NODES;
  int* wi = (int*)d_ws;
  int* gcur = wi;                                    // NB*16 = 16384 ints
  int* recs = wi + NB * 16;                          // NB*RSZ ints
  unsigned short* p1h = (unsigned short*)(recs + (size_t)NB * RSZ);
  float* q1b     = (float*)(p1h + 16 * N);           // 16N floats
  float* p2      = q1b + 16 * N;
  float* r2      = p2 + N;
  float* deg_inv = r2 + N;

  k_proj1<<<(N_NODES + 255) / 256, 256, 0, stream>>>(x, Wl1, Wr1, b1, p1h,
                                                     q1b, gcur);
  k_bscatter<<<NTILES, 512, 0, stream>>>(ei, gcur, recs);
  k_agg1<<<NB, 512, 0, stream>>>(gcur, recs, p1h, q1b, Wl2, Wr2, p2, r2,
                                 deg_inv);
  k_agg2out<<<NB, 512, 0, stream>>>(gcur, recs, p2, r2, deg_inv, b2, out);
}

// Round 9
// 356.669 us; speedup vs baseline: 1.1646x; 1.1646x over previous
//
#include <hip/hip_runtime.h>

#define N_NODES 100000
#define N_EDGES 3200000
#define NB 1024                        // buckets
#define BKN 98                         // nodes per bucket (1024*98=100352)
#define RSZ 3968                       // record window (mean 3136, +14.9 sigma)
#define TILE 6250
#define NTILES 512                     // 512*6250 == 3.2M exactly
#define MAXIT 13                       // ceil(TILE/512)
#define MAXB 8                         // ceil(RSZ/512)
#define PROJ_BLOCKS 196                // 196*512 = 100352 proj nodes

// ---------------------------------------------------------------------------
// r8 lesson: direct LDS accumulation (16 atomics/edge) serializes -> sort
// stays. r5 lesson revisited: fused middle BODY was ~75us (vs ~100 split);
// only cg::grid_group::sync (~250us sleep-spin) killed it. This round:
//   memset        : gcur + barrier counter (64KB+line)
//   k_scatterproj : grid-union -- blocks 0..511 r2 scatter, 512..707 proj
//                   (chunked channels, VGPR<=64)
//   k_mid [coop]  : r2 sortagg body (ssort/nstart/hist/r2/deg stay in LDS)
//                   -> p2 global -> HAND-ROLLED release/acquire barrier
//                   (1 atomicAdd + relaxed spin + threadfence; coop launch
//                   guarantees 1024-block co-residency = no deadlock)
//                   -> layer-2 agg from own LDS list -> out
//   fallback      : exact r2 split kernels if coop launch refused
// ---------------------------------------------------------------------------

__device__ __forceinline__ float bf2f_lo(unsigned int w) {
  return __uint_as_float(w << 16);
}
__device__ __forceinline__ float bf2f_hi(unsigned int w) {
  return __uint_as_float(w & 0xFFFF0000u);
}
__device__ __forceinline__ unsigned int f2bf(float f) {
  unsigned int b = __float_as_uint(f);
  return (b + 0x7FFFu + ((b >> 16) & 1u)) >> 16;
}

// grid-union: scatter (blocks 0..511, r2 body) + proj (blocks 512..707).
__global__ __launch_bounds__(512, 8) void k_scatterproj(
    const float* __restrict__ x, const int* __restrict__ ei,
    const float* __restrict__ Wl1, const float* __restrict__ Wr1,
    const float* __restrict__ b1, unsigned short* __restrict__ p1h,
    float* __restrict__ q1b, int* __restrict__ gcur, int* __restrict__ recs) {
  __shared__ union {
    struct {
      int hist[1024];
      int delta[NB];
      int seg[512];
      int stage[TILE];
      unsigned short bid[TILE + 6];
    } s;                                       // ~47.6 KB
    struct { float Wl[512], Wr[512], b[16]; } w;
  } u;
  const int t = threadIdx.x;
  const int kb = blockIdx.x;

  if (kb < NTILES) {
    // ---------------- r2 scatter body (verbatim) ----------------
    for (int i = t; i < 1024; i += 512) u.s.hist[i] = 0;
    __syncthreads();

    const int tb = kb * TILE;
    int rec[MAXIT], aux[MAXIT];  // aux = (bucket<<16) | rank
#pragma unroll
    for (int i = 0; i < MAXIT; ++i) {
      const int pos = t + i * 512;
      if (pos < TILE) {
        const int e = tb + pos;
        const int s = ei[e];
        const int d = ei[N_EDGES + e];
        const int k = (int)((unsigned)d / (unsigned)BKN);
        const int rank = atomicAdd(&u.s.hist[k], 1);
        rec[i] = ((d - k * BKN) << 17) | s;
        aux[i] = (k << 16) | rank;
      } else {
        aux[i] = -1;
      }
    }
    __syncthreads();

    const int s0 = u.s.hist[2 * t], s1 = u.s.hist[2 * t + 1];
    const int my = s0 + s1;
    u.s.seg[t] = my;
    __syncthreads();
#pragma unroll
    for (int o = 1; o < 512; o <<= 1) {
      const int a = (t >= o) ? u.s.seg[t - o] : 0;
      __syncthreads();
      u.s.seg[t] += a;
      __syncthreads();
    }
    const int ex = u.s.seg[t] - my;
    u.s.hist[2 * t] = ex;
    u.s.hist[2 * t + 1] = ex + s0;
    {
      const int b = 2 * t;
      if (s0) u.s.delta[b] = b * RSZ + atomicAdd(&gcur[b * 16], s0) - ex;
      if (s1)
        u.s.delta[b + 1] =
            (b + 1) * RSZ + atomicAdd(&gcur[(b + 1) * 16], s1) - (ex + s0);
    }
    __syncthreads();

#pragma unroll
    for (int i = 0; i < MAXIT; ++i) {
      if (aux[i] >= 0)
        u.s.stage[u.s.hist[aux[i] >> 16] + (aux[i] & 0xFFFF)] = rec[i];
    }
    for (int k2 = t; k2 < NB; k2 += 512) {
      const int st = u.s.hist[k2];
      const int en = (k2 == NB - 1) ? TILE : u.s.hist[k2 + 1];
      for (int p = st; p < en; ++p) u.s.bid[p] = (unsigned short)k2;
    }
    __syncthreads();

    for (int pos = t; pos < TILE; pos += 512) {
      const int bb = u.s.bid[pos];
      const int idx = u.s.delta[bb] + pos;
      if (idx < (bb + 1) * RSZ) recs[idx] = u.s.stage[pos];
    }
    return;
  }

  // ---------------- proj: one node per thread, chunked channels ----------
  u.w.Wl[t] = Wl1[t];
  u.w.Wr[t] = Wr1[t];
  if (t < 16) u.w.b[t] = b1[t];
  __syncthreads();

  const int n = (kb - NTILES) * 512 + t;
  if (n >= N_NODES) return;

  float xr[32];
  const float4* xp = (const float4*)(x + (size_t)n * 32);
#pragma unroll
  for (int j = 0; j < 8; ++j) {
    float4 v = xp[j];
    xr[4 * j + 0] = v.x;
    xr[4 * j + 1] = v.y;
    xr[4 * j + 2] = v.z;
    xr[4 * j + 3] = v.w;
  }
#pragma unroll
  for (int ch = 0; ch < 2; ++ch) {
    float pv[8], qv[8];
#pragma unroll
    for (int h2 = 0; h2 < 8; ++h2) {
      const int hh = ch * 8 + h2;
      float a = 0.f, b = 0.f;
#pragma unroll
      for (int i = 0; i < 32; ++i) {
        a = fmaf(xr[i], u.w.Wl[hh * 32 + i], a);
        b = fmaf(xr[i], u.w.Wr[hh * 32 + i], b);
      }
      pv[h2] = a;
      qv[h2] = b + u.w.b[hh];
    }
    unsigned int w[4];
#pragma unroll
    for (int j = 0; j < 4; ++j)
      w[j] = f2bf(pv[2 * j]) | (f2bf(pv[2 * j + 1]) << 16);
    ((uint4*)(p1h + (size_t)n * 16))[ch] = make_uint4(w[0], w[1], w[2], w[3]);
    float4* qp = (float4*)(q1b + (size_t)n * 16) + 2 * ch;
    qp[0] = make_float4(qv[0], qv[1], qv[2], qv[3]);
    qp[1] = make_float4(qv[4], qv[5], qv[6], qv[7]);
  }
}

// r2 sortagg body. FUSED: r2/deg stay in LDS (sr2/sdi); else go global.
template <bool FUSED>
__device__ __forceinline__ void sortagg_body(
    const int t, const int kb, const int* __restrict__ gcur,
    const int* __restrict__ recs, const unsigned short* __restrict__ p1h,
    const float* __restrict__ q1b, const float* __restrict__ Wl2,
    const float* __restrict__ Wr2, float* __restrict__ p2,
    float* __restrict__ r2g, float* __restrict__ degg, int* hist, int* nstart,
    int* ssort, float* sWl, float* sWr, float* sr2, float* sdi) {
  const int b0 = kb * RSZ;
  const int gend = b0 + min(gcur[kb * 16], RSZ);
  if (t < 128) hist[t] = 0;
  if (t < 16) {
    sWl[t] = Wl2[t];
    sWr[t] = Wr2[t];
  }
  __syncthreads();

  int rc[MAXB], ax[MAXB];  // ax = (local<<13) | rank
#pragma unroll
  for (int i = 0; i < MAXB; ++i) {
    const int r = b0 + t + i * 512;
    if (r < gend) {
      const int rv = recs[r];
      const int local = rv >> 17;
      const int rank = atomicAdd(&hist[local], 1);
      rc[i] = rv & 0x1FFFF;
      ax[i] = (local << 13) | rank;
    } else {
      ax[i] = -1;
    }
  }
  __syncthreads();

  // single-wave shuffle scan of hist[128] -> nstart (1 barrier)
  if (t < 64) {
    const int a = hist[t], b = hist[t + 64];
    int ia = a, ib = b;
#pragma unroll
    for (int o = 1; o < 64; o <<= 1) {
      const int ua = __shfl_up(ia, o);
      const int ub = __shfl_up(ib, o);
      if (t >= o) {
        ia += ua;
        ib += ub;
      }
    }
    const int tt = __shfl(ia, 63);
    nstart[t] = ia - a;
    nstart[t + 64] = tt + ib - b;
  }
  __syncthreads();

#pragma unroll
  for (int i = 0; i < MAXB; ++i) {
    if (ax[i] >= 0) ssort[nstart[ax[i] >> 13] + (ax[i] & 0x1FFF)] = rc[i];
  }
  __syncthreads();

  // aggregation: 4 lanes/node; quad = (edge-parity<<1)|channel-half
  const int quad = t & 3;
  const int half = quad & 1;
  const int epar = quad >> 1;
  const unsigned short* pb = p1h + half * 8;
  const int local = t >> 2;  // 0..127 covers BKN=98
  if (local < BKN) {
    const int n = kb * BKN + local;
    if (n < N_NODES) {
      const int st = nstart[local];
      const int k = hist[local];

      float acc[8];
#pragma unroll
      for (int i = 0; i < 8; ++i) acc[i] = 0.f;
      int j = epar;
      for (; j + 6 < k; j += 8) {
        const int s0 = ssort[st + j], s1 = ssort[st + j + 2],
                  s2 = ssort[st + j + 4], s3 = ssort[st + j + 6];
        const uint4 w0 = *(const uint4*)(pb + (size_t)s0 * 16);
        const uint4 w1 = *(const uint4*)(pb + (size_t)s1 * 16);
        const uint4 w2 = *(const uint4*)(pb + (size_t)s2 * 16);
        const uint4 w3 = *(const uint4*)(pb + (size_t)s3 * 16);
        acc[0] +=
            (bf2f_lo(w0.x) + bf2f_lo(w1.x)) + (bf2f_lo(w2.x) + bf2f_lo(w3.x));
        acc[1] +=
            (bf2f_hi(w0.x) + bf2f_hi(w1.x)) + (bf2f_hi(w2.x) + bf2f_hi(w3.x));
        acc[2] +=
            (bf2f_lo(w0.y) + bf2f_lo(w1.y)) + (bf2f_lo(w2.y) + bf2f_lo(w3.y));
        acc[3] +=
            (bf2f_hi(w0.y) + bf2f_hi(w1.y)) + (bf2f_hi(w2.y) + bf2f_hi(w3.y));
        acc[4] +=
            (bf2f_lo(w0.z) + bf2f_lo(w1.z)) + (bf2f_lo(w2.z) + bf2f_lo(w3.z));
        acc[5] +=
            (bf2f_hi(w0.z) + bf2f_hi(w1.z)) + (bf2f_hi(w2.z) + bf2f_hi(w3.z));
        acc[6] +=
            (bf2f_lo(w0.w) + bf2f_lo(w1.w)) + (bf2f_lo(w2.w) + bf2f_lo(w3.w));
        acc[7] +=
            (bf2f_hi(w0.w) + bf2f_hi(w1.w)) + (bf2f_hi(w2.w) + bf2f_hi(w3.w));
      }
      for (; j < k; j += 2) {
        const uint4 w = *(const uint4*)(pb + (size_t)ssort[st + j] * 16);
        acc[0] += bf2f_lo(w.x);
        acc[1] += bf2f_hi(w.x);
        acc[2] += bf2f_lo(w.y);
        acc[3] += bf2f_hi(w.y);
        acc[4] += bf2f_lo(w.z);
        acc[5] += bf2f_hi(w.z);
        acc[6] += bf2f_lo(w.w);
        acc[7] += bf2f_hi(w.w);
      }
#pragma unroll
      for (int i = 0; i < 8; ++i) acc[i] += __shfl_xor(acc[i], 2);

      const float di = 1.f / fmaxf((float)k, 1.f);
      const float4* qp = (const float4*)(q1b + (size_t)n * 16 + half * 8);
      const float4 qa = qp[0], qb = qp[1];
      float h[8];
      h[0] = fmaxf(fmaf(acc[0], di, qa.x), 0.f);
      h[1] = fmaxf(fmaf(acc[1], di, qa.y), 0.f);
      h[2] = fmaxf(fmaf(acc[2], di, qa.z), 0.f);
      h[3] = fmaxf(fmaf(acc[3], di, qa.w), 0.f);
      h[4] = fmaxf(fmaf(acc[4], di, qb.x), 0.f);
      h[5] = fmaxf(fmaf(acc[5], di, qb.y), 0.f);
      h[6] = fmaxf(fmaf(acc[6], di, qb.z), 0.f);
      h[7] = fmaxf(fmaf(acc[7], di, qb.w), 0.f);
      float pa = 0.f, pbv = 0.f;
#pragma unroll
      for (int i = 0; i < 8; ++i) {
        pa = fmaf(h[i], sWl[half * 8 + i], pa);
        pbv = fmaf(h[i], sWr[half * 8 + i], pbv);
      }
      pa += __shfl_xor(pa, 1);
      pbv += __shfl_xor(pbv, 1);
      if (quad == 0) {
        p2[n] = pa;
        if (FUSED) {
          sr2[local] = pbv;
          sdi[local] = di;
        } else {
          r2g[n] = pbv;
          degg[n] = di;
        }
      }
    }
  }
}

// fused middle: sortagg -> hand-rolled grid barrier -> agg2 from own LDS.
// Cooperative launch guarantees all 1024 blocks co-resident (4/CU exact).
__global__ __launch_bounds__(512, 8) void k_mid(
    const int* __restrict__ gcur, const int* __restrict__ recs,
    const unsigned short* __restrict__ p1h, const float* __restrict__ q1b,
    const float* __restrict__ Wl2, const float* __restrict__ Wr2,
    float* __restrict__ p2, const float* __restrict__ b2,
    float* __restrict__ out, int* __restrict__ bar) {
  __shared__ int hist[128], nstart[128];
  __shared__ int ssort[RSZ];
  __shared__ float sWl[16], sWr[16], sr2[BKN], sdi[BKN];
  const int t = threadIdx.x;
  const int kb = blockIdx.x;

  sortagg_body<true>(t, kb, gcur, recs, p1h, q1b, Wl2, Wr2, p2, nullptr,
                     nullptr, hist, nstart, ssort, sWl, sWr, sr2, sdi);

  // ---- hand-rolled release/acquire grid barrier (replaces cg sync) ----
  __syncthreads();  // all block stores issued (vmcnt drained at barrier)
  if (t == 0) {
    __threadfence();  // release: write back this XCD's L2
    __hip_atomic_fetch_add(bar, 1, __ATOMIC_RELEASE, __HIP_MEMORY_SCOPE_AGENT);
    while (__hip_atomic_load(bar, __ATOMIC_RELAXED, __HIP_MEMORY_SCOPE_AGENT) <
           NB) {
      __builtin_amdgcn_s_sleep(8);
    }
    __threadfence();  // acquire: invalidate stale L1/L2
  }
  __syncthreads();

  // ---- layer-2 agg straight from this block's sorted LDS list ----
  const int lane4 = t & 3;
  const int local = t >> 2;
  if (local < BKN) {
    const int n = kb * BKN + local;
    if (n < N_NODES) {
      const int st = nstart[local];
      const int k = hist[local];
      float u = 0.f;
      int j = lane4;
      for (; j + 4 < k; j += 8) {
        const int a = ssort[st + j], b = ssort[st + j + 4];
        u += p2[a] + p2[b];
      }
      for (; j < k; j += 4) u += p2[ssort[st + j]];
      u += __shfl_xor(u, 1);
      u += __shfl_xor(u, 2);
      if (lane4 == 0) out[n] = fmaf(u, sdi[local], sr2[local] + b2[0]);
    }
  }
}

// ---------------- fallback (non-cooperative, exact r2 path) ----------------
__global__ __launch_bounds__(512, 8) void k_sortagg1(
    const int* __restrict__ gcur, const int* __restrict__ recs,
    const unsigned short* __restrict__ p1h, const float* __restrict__ q1b,
    const float* __restrict__ Wl2, const float* __restrict__ Wr2,
    float* __restrict__ p2, float* __restrict__ r2,
    float* __restrict__ deg_inv) {
  __shared__ int hist[128], nstart[128];
  __shared__ int ssort[RSZ];
  __shared__ float sWl[16], sWr[16];
  sortagg_body<false>(threadIdx.x, blockIdx.x, gcur, recs, p1h, q1b, Wl2, Wr2,
                      p2, r2, deg_inv, hist, nstart, ssort, sWl, sWr, nullptr,
                      nullptr);
}

__global__ __launch_bounds__(512, 8) void k_agg2out(
    const int* __restrict__ gcur, const int* __restrict__ recs,
    const float* __restrict__ p2, const float* __restrict__ r2,
    const float* __restrict__ deg_inv, const float* __restrict__ b2,
    float* __restrict__ out) {
  __shared__ float acc[BKN];
  const int t = threadIdx.x;
  const int kb = blockIdx.x;
  if (t < BKN) acc[t] = 0.f;
  __syncthreads();

  const int b0 = kb * RSZ;
  const int cnt = min(gcur[kb * 16], RSZ);
  int r = t;
  for (; r + 1536 < cnt; r += 2048) {
    const int rv0 = recs[b0 + r];
    const int rv1 = recs[b0 + r + 512];
    const int rv2 = recs[b0 + r + 1024];
    const int rv3 = recs[b0 + r + 1536];
    const float v0 = p2[rv0 & 0x1FFFF];
    const float v1 = p2[rv1 & 0x1FFFF];
    const float v2 = p2[rv2 & 0x1FFFF];
    const float v3 = p2[rv3 & 0x1FFFF];
    atomicAdd(&acc[rv0 >> 17], v0);
    atomicAdd(&acc[rv1 >> 17], v1);
    atomicAdd(&acc[rv2 >> 17], v2);
    atomicAdd(&acc[rv3 >> 17], v3);
  }
  for (; r < cnt; r += 512) {
    const int rv = recs[b0 + r];
    atomicAdd(&acc[rv >> 17], p2[rv & 0x1FFFF]);
  }
  __syncthreads();

  if (t < BKN) {
    const int n = kb * BKN + t;
    if (n < N_NODES) out[n] = fmaf(acc[t], deg_inv[n], r2[n] + b2[0]);
  }
}

extern "C" void kernel_launch(void* const* d_in, const int* in_sizes, int n_in,
                              void* d_out, int out_size, void* d_ws,
                              size_t ws_size, hipStream_t stream) {
  const float* x   = (const float*)d_in[0];
  const int*   ei  = (const int*)d_in[1];
  const float* Wl1 = (const float*)d_in[2];
  const float* Wr1 = (const float*)d_in[3];
  const float* b1  = (const float*)d_in[4];
  const float* Wl2 = (const float*)d_in[5];
  const float* Wr2 = (const float*)d_in[6];
  const float* b2  = (const float*)d_in[7];
  float* out = (float*)d_out;

  const size_t N = N_NODES;
  int* wi = (int*)d_ws;
  int* gcur = wi;                                    // NB*16 ints
  int* bar  = wi + NB * 16;                          // barrier counter (+pad)
  int* recs = bar + 16;                              // NB*RSZ ints
  unsigned short* p1h = (unsigned short*)(recs + (size_t)NB * RSZ);
  float* q1b     = (float*)(p1h + 16 * N);           // 16N floats
  float* p2      = q1b + 16 * N;
  float* r2      = p2 + N;                           // fallback only
  float* deg_inv = r2 + N;                           // fallback only

  hipMemsetAsync(gcur, 0, (NB * 16 + 16) * sizeof(int), stream);
  k_scatterproj<<<NTILES + PROJ_BLOCKS, 512, 0, stream>>>(x, ei, Wl1, Wr1, b1,
                                                          p1h, q1b, gcur,
                                                          recs);

  void* ka[] = {(void*)&gcur, (void*)&recs, (void*)&p1h, (void*)&q1b,
                (void*)&Wl2,  (void*)&Wr2,  (void*)&p2,  (void*)&b2,
                (void*)&out,  (void*)&bar};
  hipError_t err = hipLaunchCooperativeKernel(
      reinterpret_cast<void*>(k_mid), dim3(NB), dim3(512), ka, 0, stream);
  if (err != hipSuccess) {
    (void)hipGetLastError();  // clear sticky error, use split fallback
    k_sortagg1<<<NB, 512, 0, stream>>>(gcur, recs, p1h, q1b, Wl2, Wr2, p2, r2,
                                       deg_inv);
    k_agg2out<<<NB, 512, 0, stream>>>(gcur, recs, p2, r2, deg_inv, b2, out);
  }
}

// Round 10
// 172.133 us; speedup vs baseline: 2.4132x; 2.0721x over previous
//
#include <hip/hip_runtime.h>

#define N_NODES 100000
#define N_EDGES 3200000
#define NB 1024                        // buckets
#define BKN 98                         // nodes per bucket (1024*98=100352)
#define RSZ 3968                       // record window (mean 3136, +14.9 sigma)
#define TILE 6250
#define NTILES 512                     // 512*6250 == 3.2M exactly
#define MAXIT 13                       // ceil(TILE/512)
#define PROJ_BLOCKS 196                // 196*512 = 100352 proj nodes

// ---------------------------------------------------------------------------
// Ledger: grid-wide fusion dead (r1 425 / r5 325 / r9 357us: barrier >=120us
// regardless of mechanism). Scatter write-amp fix neutral (r6). Atomic-free
// neutral (r4). Direct-accumulate catastrophic (r8). Best = r2 4-dispatch 172.
// This round: r2 bodies, minus one boundary (proj unioned into scatter grid,
// verified in r9), plus gather-ILP: int4 record loads + 8-wide gather unroll.
//   memset gcur   -> k_scatterproj (scatter blocks 0..511 || proj 512..707)
//                 -> k_sortagg1 (int4 loads, 8-wide agg gathers)
//                 -> k_agg2out  (int4 loads, 8 gathers in flight)
// ---------------------------------------------------------------------------

__device__ __forceinline__ float bf2f_lo(unsigned int w) {
  return __uint_as_float(w << 16);
}
__device__ __forceinline__ float bf2f_hi(unsigned int w) {
  return __uint_as_float(w & 0xFFFF0000u);
}
__device__ __forceinline__ unsigned int f2bf(float f) {
  unsigned int b = __float_as_uint(f);
  return (b + 0x7FFFu + ((b >> 16) & 1u)) >> 16;
}

// grid-union: scatter (blocks 0..511, r2 body) + proj (blocks 512..707).
__global__ __launch_bounds__(512, 8) void k_scatterproj(
    const float* __restrict__ x, const int* __restrict__ ei,
    const float* __restrict__ Wl1, const float* __restrict__ Wr1,
    const float* __restrict__ b1, unsigned short* __restrict__ p1h,
    float* __restrict__ q1b, int* __restrict__ gcur, int* __restrict__ recs) {
  __shared__ union {
    struct {
      int hist[1024];
      int delta[NB];
      int seg[512];
      int stage[TILE];
      unsigned short bid[TILE + 6];
    } s;                                       // ~47.6 KB
    struct { float Wl[512], Wr[512], b[16]; } w;
  } u;
  const int t = threadIdx.x;
  const int kb = blockIdx.x;

  if (kb < NTILES) {
    // ---------------- r2 scatter body (verbatim) ----------------
    for (int i = t; i < 1024; i += 512) u.s.hist[i] = 0;
    __syncthreads();

    const int tb = kb * TILE;
    int rec[MAXIT], aux[MAXIT];  // aux = (bucket<<16) | rank
#pragma unroll
    for (int i = 0; i < MAXIT; ++i) {
      const int pos = t + i * 512;
      if (pos < TILE) {
        const int e = tb + pos;
        const int s = ei[e];
        const int d = ei[N_EDGES + e];
        const int k = (int)((unsigned)d / (unsigned)BKN);
        const int rank = atomicAdd(&u.s.hist[k], 1);
        rec[i] = ((d - k * BKN) << 17) | s;
        aux[i] = (k << 16) | rank;
      } else {
        aux[i] = -1;
      }
    }
    __syncthreads();

    const int s0 = u.s.hist[2 * t], s1 = u.s.hist[2 * t + 1];
    const int my = s0 + s1;
    u.s.seg[t] = my;
    __syncthreads();
#pragma unroll
    for (int o = 1; o < 512; o <<= 1) {
      const int a = (t >= o) ? u.s.seg[t - o] : 0;
      __syncthreads();
      u.s.seg[t] += a;
      __syncthreads();
    }
    const int ex = u.s.seg[t] - my;
    u.s.hist[2 * t] = ex;
    u.s.hist[2 * t + 1] = ex + s0;
    {
      const int b = 2 * t;
      if (s0) u.s.delta[b] = b * RSZ + atomicAdd(&gcur[b * 16], s0) - ex;
      if (s1)
        u.s.delta[b + 1] =
            (b + 1) * RSZ + atomicAdd(&gcur[(b + 1) * 16], s1) - (ex + s0);
    }
    __syncthreads();

#pragma unroll
    for (int i = 0; i < MAXIT; ++i) {
      if (aux[i] >= 0)
        u.s.stage[u.s.hist[aux[i] >> 16] + (aux[i] & 0xFFFF)] = rec[i];
    }
    for (int k2 = t; k2 < NB; k2 += 512) {
      const int st = u.s.hist[k2];
      const int en = (k2 == NB - 1) ? TILE : u.s.hist[k2 + 1];
      for (int p = st; p < en; ++p) u.s.bid[p] = (unsigned short)k2;
    }
    __syncthreads();

    for (int pos = t; pos < TILE; pos += 512) {
      const int bb = u.s.bid[pos];
      const int idx = u.s.delta[bb] + pos;
      if (idx < (bb + 1) * RSZ) recs[idx] = u.s.stage[pos];
    }
    return;
  }

  // ---------------- proj: one node per thread, chunked channels ----------
  u.w.Wl[t] = Wl1[t];
  u.w.Wr[t] = Wr1[t];
  if (t < 16) u.w.b[t] = b1[t];
  __syncthreads();

  const int n = (kb - NTILES) * 512 + t;
  if (n >= N_NODES) return;

  float xr[32];
  const float4* xp = (const float4*)(x + (size_t)n * 32);
#pragma unroll
  for (int j = 0; j < 8; ++j) {
    float4 v = xp[j];
    xr[4 * j + 0] = v.x;
    xr[4 * j + 1] = v.y;
    xr[4 * j + 2] = v.z;
    xr[4 * j + 3] = v.w;
  }
#pragma unroll
  for (int ch = 0; ch < 2; ++ch) {
    float pv[8], qv[8];
#pragma unroll
    for (int h2 = 0; h2 < 8; ++h2) {
      const int hh = ch * 8 + h2;
      float a = 0.f, b = 0.f;
#pragma unroll
      for (int i = 0; i < 32; ++i) {
        a = fmaf(xr[i], u.w.Wl[hh * 32 + i], a);
        b = fmaf(xr[i], u.w.Wr[hh * 32 + i], b);
      }
      pv[h2] = a;
      qv[h2] = b + u.w.b[hh];
    }
    unsigned int w[4];
#pragma unroll
    for (int j = 0; j < 4; ++j)
      w[j] = f2bf(pv[2 * j]) | (f2bf(pv[2 * j + 1]) << 16);
    ((uint4*)(p1h + (size_t)n * 16))[ch] = make_uint4(w[0], w[1], w[2], w[3]);
    float4* qp = (float4*)(q1b + (size_t)n * 16) + 2 * ch;
    qp[0] = make_float4(qv[0], qv[1], qv[2], qv[3]);
    qp[1] = make_float4(qv[4], qv[5], qv[6], qv[7]);
  }
}

// Per-bucket LDS counting sort + layer-1 agg + layer-2 proj (r2 body,
// int4 record loads + 8-wide gather unroll). 1024 x 512 = 4 blocks/CU.
__global__ __launch_bounds__(512, 8) void k_sortagg1(
    const int* __restrict__ gcur, const int* __restrict__ recs,
    const unsigned short* __restrict__ p1h, const float* __restrict__ q1b,
    const float* __restrict__ Wl2, const float* __restrict__ Wr2,
    float* __restrict__ p2, float* __restrict__ r2,
    float* __restrict__ deg_inv) {
  __shared__ int hist[128], nstart[128];
  __shared__ int ssort[RSZ];
  __shared__ float sWl[16], sWr[16];
  const int t = threadIdx.x;
  const int kb = blockIdx.x;
  const int cend = min(gcur[kb * 16], RSZ);
  if (t < 128) hist[t] = 0;
  if (t < 16) {
    sWl[t] = Wl2[t];
    sWr[t] = Wr2[t];
  }
  __syncthreads();

  // int4 record load (RSZ/4 = 992 -> 2 rounds of 512)
  const int4* r4 = (const int4*)(recs + (size_t)kb * RSZ);
  int rc[8], ax[8];  // ax = (local<<13) | rank
#pragma unroll
  for (int i = 0; i < 2; ++i) {
    const int idx = t + i * 512;
    const int base = 4 * idx;
    ax[4 * i + 0] = ax[4 * i + 1] = ax[4 * i + 2] = ax[4 * i + 3] = -1;
    if (idx < RSZ / 4 && base < cend) {
      const int4 v = r4[idx];
      {
        const int l = v.x >> 17;
        rc[4 * i + 0] = v.x & 0x1FFFF;
        ax[4 * i + 0] = (l << 13) | atomicAdd(&hist[l], 1);
      }
      if (base + 1 < cend) {
        const int l = v.y >> 17;
        rc[4 * i + 1] = v.y & 0x1FFFF;
        ax[4 * i + 1] = (l << 13) | atomicAdd(&hist[l], 1);
      }
      if (base + 2 < cend) {
        const int l = v.z >> 17;
        rc[4 * i + 2] = v.z & 0x1FFFF;
        ax[4 * i + 2] = (l << 13) | atomicAdd(&hist[l], 1);
      }
      if (base + 3 < cend) {
        const int l = v.w >> 17;
        rc[4 * i + 3] = v.w & 0x1FFFF;
        ax[4 * i + 3] = (l << 13) | atomicAdd(&hist[l], 1);
      }
    }
  }
  __syncthreads();

  // single-wave shuffle scan of hist[128] -> nstart (1 barrier)
  if (t < 64) {
    const int a = hist[t], b = hist[t + 64];
    int ia = a, ib = b;
#pragma unroll
    for (int o = 1; o < 64; o <<= 1) {
      const int ua = __shfl_up(ia, o);
      const int ub = __shfl_up(ib, o);
      if (t >= o) {
        ia += ua;
        ib += ub;
      }
    }
    const int tt = __shfl(ia, 63);
    nstart[t] = ia - a;
    nstart[t + 64] = tt + ib - b;
  }
  __syncthreads();

#pragma unroll
  for (int i = 0; i < 8; ++i) {
    if (ax[i] >= 0) ssort[nstart[ax[i] >> 13] + (ax[i] & 0x1FFF)] = rc[i];
  }
  __syncthreads();

  // aggregation: 4 lanes/node; quad = (edge-parity<<1)|channel-half
  const int quad = t & 3;
  const int half = quad & 1;
  const int epar = quad >> 1;
  const unsigned short* pb = p1h + half * 8;
  const int local = t >> 2;  // 0..127 covers BKN=98
  if (local < BKN) {
    const int n = kb * BKN + local;
    if (n < N_NODES) {
      const int st = nstart[local];
      const int k = hist[local];

      float acc[8];
#pragma unroll
      for (int i = 0; i < 8; ++i) acc[i] = 0.f;
      int j = epar;
      // 8 independent 16B gathers in flight per iteration
      for (; j + 14 < k; j += 16) {
        const int s0 = ssort[st + j], s1 = ssort[st + j + 2],
                  s2 = ssort[st + j + 4], s3 = ssort[st + j + 6],
                  s4 = ssort[st + j + 8], s5 = ssort[st + j + 10],
                  s6 = ssort[st + j + 12], s7 = ssort[st + j + 14];
        const uint4 w0 = *(const uint4*)(pb + (size_t)s0 * 16);
        const uint4 w1 = *(const uint4*)(pb + (size_t)s1 * 16);
        const uint4 w2 = *(const uint4*)(pb + (size_t)s2 * 16);
        const uint4 w3 = *(const uint4*)(pb + (size_t)s3 * 16);
        const uint4 w4 = *(const uint4*)(pb + (size_t)s4 * 16);
        const uint4 w5 = *(const uint4*)(pb + (size_t)s5 * 16);
        const uint4 w6 = *(const uint4*)(pb + (size_t)s6 * 16);
        const uint4 w7 = *(const uint4*)(pb + (size_t)s7 * 16);
        acc[0] += ((bf2f_lo(w0.x) + bf2f_lo(w1.x)) +
                   (bf2f_lo(w2.x) + bf2f_lo(w3.x))) +
                  ((bf2f_lo(w4.x) + bf2f_lo(w5.x)) +
                   (bf2f_lo(w6.x) + bf2f_lo(w7.x)));
        acc[1] += ((bf2f_hi(w0.x) + bf2f_hi(w1.x)) +
                   (bf2f_hi(w2.x) + bf2f_hi(w3.x))) +
                  ((bf2f_hi(w4.x) + bf2f_hi(w5.x)) +
                   (bf2f_hi(w6.x) + bf2f_hi(w7.x)));
        acc[2] += ((bf2f_lo(w0.y) + bf2f_lo(w1.y)) +
                   (bf2f_lo(w2.y) + bf2f_lo(w3.y))) +
                  ((bf2f_lo(w4.y) + bf2f_lo(w5.y)) +
                   (bf2f_lo(w6.y) + bf2f_lo(w7.y)));
        acc[3] += ((bf2f_hi(w0.y) + bf2f_hi(w1.y)) +
                   (bf2f_hi(w2.y) + bf2f_hi(w3.y))) +
                  ((bf2f_hi(w4.y) + bf2f_hi(w5.y)) +
                   (bf2f_hi(w6.y) + bf2f_hi(w7.y)));
        acc[4] += ((bf2f_lo(w0.z) + bf2f_lo(w1.z)) +
                   (bf2f_lo(w2.z) + bf2f_lo(w3.z))) +
                  ((bf2f_lo(w4.z) + bf2f_lo(w5.z)) +
                   (bf2f_lo(w6.z) + bf2f_lo(w7.z)));
        acc[5] += ((bf2f_hi(w0.z) + bf2f_hi(w1.z)) +
                   (bf2f_hi(w2.z) + bf2f_hi(w3.z))) +
                  ((bf2f_hi(w4.z) + bf2f_hi(w5.z)) +
                   (bf2f_hi(w6.z) + bf2f_hi(w7.z)));
        acc[6] += ((bf2f_lo(w0.w) + bf2f_lo(w1.w)) +
                   (bf2f_lo(w2.w) + bf2f_lo(w3.w))) +
                  ((bf2f_lo(w4.w) + bf2f_lo(w5.w)) +
                   (bf2f_lo(w6.w) + bf2f_lo(w7.w)));
        acc[7] += ((bf2f_hi(w0.w) + bf2f_hi(w1.w)) +
                   (bf2f_hi(w2.w) + bf2f_hi(w3.w))) +
                  ((bf2f_hi(w4.w) + bf2f_hi(w5.w)) +
                   (bf2f_hi(w6.w) + bf2f_hi(w7.w)));
      }
      for (; j < k; j += 2) {
        const uint4 w = *(const uint4*)(pb + (size_t)ssort[st + j] * 16);
        acc[0] += bf2f_lo(w.x);
        acc[1] += bf2f_hi(w.x);
        acc[2] += bf2f_lo(w.y);
        acc[3] += bf2f_hi(w.y);
        acc[4] += bf2f_lo(w.z);
        acc[5] += bf2f_hi(w.z);
        acc[6] += bf2f_lo(w.w);
        acc[7] += bf2f_hi(w.w);
      }
#pragma unroll
      for (int i = 0; i < 8; ++i) acc[i] += __shfl_xor(acc[i], 2);

      const float di = 1.f / fmaxf((float)k, 1.f);
      const float4* qp = (const float4*)(q1b + (size_t)n * 16 + half * 8);
      const float4 qa = qp[0], qb = qp[1];
      float h[8];
      h[0] = fmaxf(fmaf(acc[0], di, qa.x), 0.f);
      h[1] = fmaxf(fmaf(acc[1], di, qa.y), 0.f);
      h[2] = fmaxf(fmaf(acc[2], di, qa.z), 0.f);
      h[3] = fmaxf(fmaf(acc[3], di, qa.w), 0.f);
      h[4] = fmaxf(fmaf(acc[4], di, qb.x), 0.f);
      h[5] = fmaxf(fmaf(acc[5], di, qb.y), 0.f);
      h[6] = fmaxf(fmaf(acc[6], di, qb.z), 0.f);
      h[7] = fmaxf(fmaf(acc[7], di, qb.w), 0.f);
      float pa = 0.f, pbv = 0.f;
#pragma unroll
      for (int i = 0; i < 8; ++i) {
        pa = fmaf(h[i], sWl[half * 8 + i], pa);
        pbv = fmaf(h[i], sWr[half * 8 + i], pbv);
      }
      pa += __shfl_xor(pa, 1);
      pbv += __shfl_xor(pbv, 1);
      if (quad == 0) {
        p2[n] = pa;
        r2[n] = pbv;
        deg_inv[n] = di;
      }
    }
  }
}

// layer-2 aggregation: int4 recs loads (8 gathers in flight), LDS atomicAdd.
__global__ __launch_bounds__(512, 8) void k_agg2out(
    const int* __restrict__ gcur, const int* __restrict__ recs,
    const float* __restrict__ p2, const float* __restrict__ r2,
    const float* __restrict__ deg_inv, const float* __restrict__ b2,
    float* __restrict__ out) {
  __shared__ float acc[BKN];
  const int t = threadIdx.x;
  const int kb = blockIdx.x;
  if (t < BKN) acc[t] = 0.f;
  __syncthreads();

  const int cnt = min(gcur[kb * 16], RSZ);
  const int4* r4 = (const int4*)(recs + (size_t)kb * RSZ);
#pragma unroll
  for (int i = 0; i < 2; ++i) {  // RSZ/4 = 992 -> 2 rounds of 512
    const int idx = t + i * 512;
    const int base = 4 * idx;
    if (idx < RSZ / 4 && base < cnt) {
      const int4 v = r4[idx];
      const bool b1v = base + 1 < cnt, b2v = base + 2 < cnt,
                 b3v = base + 3 < cnt;
      const float g0 = p2[v.x & 0x1FFFF];
      const float g1 = b1v ? p2[v.y & 0x1FFFF] : 0.f;
      const float g2 = b2v ? p2[v.z & 0x1FFFF] : 0.f;
      const float g3 = b3v ? p2[v.w & 0x1FFFF] : 0.f;
      atomicAdd(&acc[v.x >> 17], g0);
      if (b1v) atomicAdd(&acc[v.y >> 17], g1);
      if (b2v) atomicAdd(&acc[v.z >> 17], g2);
      if (b3v) atomicAdd(&acc[v.w >> 17], g3);
    }
  }
  __syncthreads();

  if (t < BKN) {
    const int n = kb * BKN + t;
    if (n < N_NODES) out[n] = fmaf(acc[t], deg_inv[n], r2[n] + b2[0]);
  }
}

extern "C" void kernel_launch(void* const* d_in, const int* in_sizes, int n_in,
                              void* d_out, int out_size, void* d_ws,
                              size_t ws_size, hipStream_t stream) {
  const float* x   = (const float*)d_in[0];
  const int*   ei  = (const int*)d_in[1];
  const float* Wl1 = (const float*)d_in[2];
  const float* Wr1 = (const float*)d_in[3];
  const float* b1  = (const float*)d_in[4];
  const float* Wl2 = (const float*)d_in[5];
  const float* Wr2 = (const float*)d_in[6];
  const float* b2  = (const float*)d_in[7];
  float* out = (float*)d_out;

  const size_t N = N_NODES;
  int* wi = (int*)d_ws;
  int* gcur = wi;                                    // NB*16 ints (64 KB)
  int* recs = wi + NB * 16;                          // NB*RSZ ints
  unsigned short* p1h = (unsigned short*)(recs + (size_t)NB * RSZ);
  float* q1b     = (float*)(p1h + 16 * N);           // 16N floats
  float* p2      = q1b + 16 * N;
  float* r2      = p2 + N;
  float* deg_inv = r2 + N;

  hipMemsetAsync(gcur, 0, NB * 16 * sizeof(int), stream);
  k_scatterproj<<<NTILES + PROJ_BLOCKS, 512, 0, stream>>>(x, ei, Wl1, Wr1, b1,
                                                          p1h, q1b, gcur,
                                                          recs);
  k_sortagg1<<<NB, 512, 0, stream>>>(gcur, recs, p1h, q1b, Wl2, Wr2, p2, r2,
                                     deg_inv);
  k_agg2out<<<NB, 512, 0, stream>>>(gcur, recs, p2, r2, deg_inv, b2, out);
}